// Round 1
// baseline (23.702 us; speedup 1.0000x reference)
//
#include <hip/hip_runtime.h>
#include <math.h>

// Problem constants (from setup_inputs): heatmap [64,17,128,128] f32, targets [64,17,3] f32.
constexpr int Bc  = 64;
constexpr int Kc  = 17;
constexpr int Hc  = 128;
constexpr int Wc  = 128;
constexpr int HWc = Hc * Wc;   // 16384
constexpr int NBK = Bc * Kc;   // 1088

// Kernel 1: one block per (b,k) row.
//  - 256 threads x 64 floats each (16x float4, coalesced), kept in registers
//  - block-reduce max, then sum of exp(x - max)  -> lse
//  - wave 0 gathers the <=25 Gaussian-window elements and forms
//      per_bk = sum(g*log g) - sum(g*h) + lse * sum(g)
//  - writes per_bk*vis and vis to workspace (deterministic two-stage reduce)
__global__ __launch_bounds__(256) void kl_rowloss(const float* __restrict__ heatmap,
                                                  const float* __restrict__ targets,
                                                  float* __restrict__ ws) {
    const int bk  = blockIdx.x;
    const int tid = threadIdx.x;
    const float*  __restrict__ row  = heatmap + (size_t)bk * HWc;
    const float4* __restrict__ row4 = reinterpret_cast<const float4*>(row);

    float4 v[16];
#pragma unroll
    for (int c = 0; c < 16; ++c) v[c] = row4[c * 256 + tid];

    // ---- block max ----
    float m = -3.4e38f;
#pragma unroll
    for (int c = 0; c < 16; ++c)
        m = fmaxf(m, fmaxf(fmaxf(v[c].x, v[c].y), fmaxf(v[c].z, v[c].w)));
#pragma unroll
    for (int off = 32; off; off >>= 1)
        m = fmaxf(m, __shfl_xor(m, off));

    __shared__ float smax[4];
    __shared__ float ssum[4];
    const int wave = tid >> 6;
    if ((tid & 63) == 0) smax[wave] = m;
    __syncthreads();
    m = fmaxf(fmaxf(smax[0], smax[1]), fmaxf(smax[2], smax[3]));

    // ---- sum of exp(x - m) ----
    float s = 0.f;
#pragma unroll
    for (int c = 0; c < 16; ++c) {
        s += expf(v[c].x - m) + expf(v[c].y - m) +
             expf(v[c].z - m) + expf(v[c].w - m);
    }
#pragma unroll
    for (int off = 32; off; off >>= 1)
        s += __shfl_xor(s, off);
    if ((tid & 63) == 0) ssum[wave] = s;
    __syncthreads();

    if (wave == 0) {
        const float S   = ssum[0] + ssum[1] + ssum[2] + ssum[3];
        const float lse = m + logf(S);

        // ---- Gaussian window (5x5, sigma=0.5), zero-padded 'SAME' semantics ----
        float c_gh = 0.f, c_g = 0.f, c_glg = 0.f;
        if (tid < 25) {
            const int dy = tid / 5 - 2;
            const int dx = tid % 5 - 2;
            const int tx = __float2int_rn(targets[bk * 3 + 0]) + dx;
            const int ty = __float2int_rn(targets[bk * 3 + 1]) + dy;
            if (tx >= 0 && tx < Wc && ty >= 0 && ty < Hc) {
                const float s1   = 1.f + 2.f * expf(-2.f) + 2.f * expf(-8.f);
                const float norm = s1 * s1;                       // k2.sum()
                const float g    = expf(-2.f * (float)(dx * dx + dy * dy)) / norm;
                c_g   = g;
                c_gh  = g * row[ty * Wc + tx];
                c_glg = g * logf(g);
            }
        }
#pragma unroll
        for (int off = 16; off; off >>= 1) {   // lanes 25..63 hold zeros
            c_gh  += __shfl_xor(c_gh,  off);
            c_g   += __shfl_xor(c_g,   off);
            c_glg += __shfl_xor(c_glg, off);
        }
        if (tid == 0) {
            const int vis = __float2int_rn(targets[bk * 3 + 2]) > 0;
            const float per = c_glg - c_gh + lse * c_g;
            ws[bk]       = vis ? per : 0.f;
            ws[NBK + bk] = vis ? 1.f : 0.f;
        }
    }
}

// Kernel 2: reduce the 1088 per-keypoint terms and the visible count.
__global__ __launch_bounds__(256) void kl_finalize(const float* __restrict__ ws,
                                                   float* __restrict__ out) {
    const int tid = threadIdx.x;
    float a = 0.f, n = 0.f;
    for (int i = tid; i < NBK; i += 256) {
        a += ws[i];
        n += ws[NBK + i];
    }
#pragma unroll
    for (int off = 32; off; off >>= 1) {
        a += __shfl_xor(a, off);
        n += __shfl_xor(n, off);
    }
    __shared__ float sa[4];
    __shared__ float sn[4];
    const int wave = tid >> 6;
    if ((tid & 63) == 0) { sa[wave] = a; sn[wave] = n; }
    __syncthreads();
    if (tid == 0) {
        a = sa[0] + sa[1] + sa[2] + sa[3];
        n = sn[0] + sn[1] + sn[2] + sn[3];
        out[0] = a / fmaxf(n, 1.f);
    }
}

extern "C" void kernel_launch(void* const* d_in, const int* in_sizes, int n_in,
                              void* d_out, int out_size, void* d_ws, size_t ws_size,
                              hipStream_t stream) {
    const float* heatmap = (const float*)d_in[0];
    const float* targets = (const float*)d_in[1];
    float* ws  = (float*)d_ws;
    float* out = (float*)d_out;

    kl_rowloss<<<NBK, 256, 0, stream>>>(heatmap, targets, ws);
    kl_finalize<<<1, 256, 0, stream>>>(ws, out);
}

// Round 2
// 23.333 us; speedup vs baseline: 1.0158x; 1.0158x over previous
//
#include <hip/hip_runtime.h>
#include <math.h>

// heatmap [64,17,128,128] f32, targets [64,17,3] f32 (x, y, visible)
constexpr int Bc     = 64;
constexpr int Kc     = 17;
constexpr int Hc     = 128;
constexpr int Wc     = 128;
constexpr int HWc    = Hc * Wc;          // 16384
constexpr int NBK    = Bc * Kc;          // 1088
constexpr int NCHUNK = 4;                // chunks per (b,k) row
constexpr int CHUNK  = HWc / NCHUNK;     // 4096 elements = 32 image rows
constexpr int NBLK   = NBK * NCHUNK;     // 4352 blocks

// Kernel 1: one block per (bk, chunk).
//  - 256 threads x 16 floats (4x float4, coalesced) -> low VGPR, high occupancy
//  - block-reduce chunk max, then chunk sum of exp(x - m)
//  - lanes 0..24 accumulate the partial Gaussian-window dot product for
//    window cells whose image row falls inside this chunk (L1-resident)
//  - writes (m, s, gh) per chunk to ws
__global__ __launch_bounds__(256) void kl_chunk(const float* __restrict__ hm,
                                                const float* __restrict__ tg,
                                                float* __restrict__ ws) {
    const int bx    = blockIdx.x;
    const int bk    = bx >> 2;
    const int chunk = bx & 3;
    const int tid   = threadIdx.x;

    const float*  __restrict__ base  = hm + (size_t)bk * HWc + (size_t)chunk * CHUNK;
    const float4* __restrict__ base4 = reinterpret_cast<const float4*>(base);

    float4 v[4];
#pragma unroll
    for (int c = 0; c < 4; ++c) v[c] = base4[c * 256 + tid];

    // ---- partial gaussian-window dot product (issue early, hides latency) ----
    float gh = 0.f;
    if (tid < 25) {
        const int dy = tid / 5 - 2;
        const int dx = tid % 5 - 2;
        const int tx = __float2int_rn(tg[bk * 3 + 0]) + dx;
        const int ty = __float2int_rn(tg[bk * 3 + 1]) + dy;
        const int r0 = chunk * (Hc / NCHUNK);
        if (tx >= 0 && tx < Wc && ty >= r0 && ty < r0 + Hc / NCHUNK) {
            const float s1   = 1.f + 2.f * expf(-2.f) + 2.f * expf(-8.f);
            const float g    = expf(-2.f * (float)(dx * dx + dy * dy)) / (s1 * s1);
            gh = g * hm[(size_t)bk * HWc + ty * Wc + tx];
        }
    }

    // ---- chunk max ----
    float m = -3.4e38f;
#pragma unroll
    for (int c = 0; c < 4; ++c)
        m = fmaxf(m, fmaxf(fmaxf(v[c].x, v[c].y), fmaxf(v[c].z, v[c].w)));
#pragma unroll
    for (int off = 32; off; off >>= 1)
        m = fmaxf(m, __shfl_xor(m, off));

    __shared__ float smax[4];
    __shared__ float ssum[4];
    const int wave = tid >> 6;
    if ((tid & 63) == 0) smax[wave] = m;
    __syncthreads();
    m = fmaxf(fmaxf(smax[0], smax[1]), fmaxf(smax[2], smax[3]));

    // ---- chunk sum of exp(x - m) ----
    float s = 0.f;
#pragma unroll
    for (int c = 0; c < 4; ++c) {
        s += expf(v[c].x - m) + expf(v[c].y - m) +
             expf(v[c].z - m) + expf(v[c].w - m);
    }
#pragma unroll
    for (int off = 32; off; off >>= 1)
        s += __shfl_xor(s, off);
    if ((tid & 63) == 0) ssum[wave] = s;
    __syncthreads();

    if (wave == 0) {
        // reduce gh over lanes 0..31 (lanes 25..63 hold zero)
#pragma unroll
        for (int off = 16; off; off >>= 1)
            gh += __shfl_xor(gh, off);
        if (tid == 0) {
            const float S = ssum[0] + ssum[1] + ssum[2] + ssum[3];
            ws[bx]            = m;
            ws[NBLK + bx]     = S;
            ws[2 * NBLK + bx] = gh;
        }
    }
}

// Kernel 2 (single block): per-(b,k) combine the 4 chunk partials, form the
// closed-form window constants from the bounds mask, and reduce the
// vis-weighted batchmean.
__global__ __launch_bounds__(256) void kl_final(const float* __restrict__ ws,
                                                const float* __restrict__ tg,
                                                float* __restrict__ out) {
    const int tid = threadIdx.x;
    const float s1   = 1.f + 2.f * expf(-2.f) + 2.f * expf(-8.f);
    const float norm = s1 * s1;

    float acc = 0.f, nv = 0.f;
    for (int bk = tid; bk < NBK; bk += 256) {
        const float4 mv = *reinterpret_cast<const float4*>(ws + 4 * bk);
        const float4 sv = *reinterpret_cast<const float4*>(ws + NBLK + 4 * bk);
        const float4 gv = *reinterpret_cast<const float4*>(ws + 2 * NBLK + 4 * bk);

        const float M = fmaxf(fmaxf(mv.x, mv.y), fmaxf(mv.z, mv.w));
        const float S = sv.x * expf(mv.x - M) + sv.y * expf(mv.y - M) +
                        sv.z * expf(mv.z - M) + sv.w * expf(mv.w - M);
        const float lse = M + logf(S);
        const float gh  = gv.x + gv.y + gv.z + gv.w;

        const int tx  = __float2int_rn(tg[bk * 3 + 0]);
        const int ty  = __float2int_rn(tg[bk * 3 + 1]);
        const int vis = __float2int_rn(tg[bk * 3 + 2]) > 0;

        float cg = 0.f, cglg = 0.f;
#pragma unroll
        for (int i = 0; i < 25; ++i) {
            const int dy = i / 5 - 2;
            const int dx = i % 5 - 2;
            const int x = tx + dx, y = ty + dy;
            if (x >= 0 && x < Wc && y >= 0 && y < Hc) {
                const float g = expf(-2.f * (float)(dx * dx + dy * dy)) / norm;
                cg   += g;
                cglg += g * logf(g);
            }
        }
        const float per = cglg - gh + lse * cg;
        if (vis) { acc += per; nv += 1.f; }
    }

#pragma unroll
    for (int off = 32; off; off >>= 1) {
        acc += __shfl_xor(acc, off);
        nv  += __shfl_xor(nv,  off);
    }
    __shared__ float sa[4];
    __shared__ float sn[4];
    const int wave = tid >> 6;
    if ((tid & 63) == 0) { sa[wave] = acc; sn[wave] = nv; }
    __syncthreads();
    if (tid == 0) {
        acc = sa[0] + sa[1] + sa[2] + sa[3];
        nv  = sn[0] + sn[1] + sn[2] + sn[3];
        out[0] = acc / fmaxf(nv, 1.f);
    }
}

extern "C" void kernel_launch(void* const* d_in, const int* in_sizes, int n_in,
                              void* d_out, int out_size, void* d_ws, size_t ws_size,
                              hipStream_t stream) {
    const float* heatmap = (const float*)d_in[0];
    const float* targets = (const float*)d_in[1];
    float* ws  = (float*)d_ws;
    float* out = (float*)d_out;

    kl_chunk<<<NBLK, 256, 0, stream>>>(heatmap, targets, ws);
    kl_final<<<1, 256, 0, stream>>>(ws, targets, out);
}